// Round 2
// baseline (78.784 us; speedup 1.0000x reference)
//
#include <hip/hip_runtime.h>

#define NTOK 16384
#define HID  4096
#define NEXP 64
#define BM   32
#define BK   64
#define NSTEPS (HID / BK)       // 64
#define PLANE  (NEXP * HID)     // 262144 f16 elems per plane (512 KB)

typedef _Float16 f16;
typedef f16  f16x4 __attribute__((ext_vector_type(4)));
typedef f16  f16x8 __attribute__((ext_vector_type(8)));
typedef float f32x4 __attribute__((ext_vector_type(4)));

// LDS A planes: [row][64 k] fp16, row stride 128 B = 8 units of 16 B.
// XOR-swizzle unit with (row&7): fragment reads (16 rows, same unit) spread
// across all 8 bank-quads -> 2-way aliasing = free.
__device__ __forceinline__ int swz(int row, int unit16) {
    return row * 64 + ((unit16 ^ (row & 7)) << 3);
}

// ---- pack w -> fragment-ordered fp16 hi/lo planes in workspace ----
// Layout: wp[plane][ks(128)][g(4)][lane(64)][j(8)], where for lane l:
//   expert e = g*16 + (l&15), k = ks*32 + (l>>4)*8 + j.
// A wave's B-fragment load is then 64 lanes x 16 B, fully contiguous (1 KB).
__global__ __launch_bounds__(256)
void pack_w_kernel(const float* __restrict__ w, f16* __restrict__ wp) {
    int tid = blockIdx.x * 256 + threadIdx.x;   // 32768 threads
    int e = tid >> 9;                           // 0..63
    int k = (tid & 511) << 3;                   // 0..4088, step 8
    const float* src = w + (size_t)e * HID + k;
    float4 v0 = *(const float4*)(src);
    float4 v1 = *(const float4*)(src + 4);
    float sv[8] = {v0.x, v0.y, v0.z, v0.w, v1.x, v1.y, v1.z, v1.w};
    f16x8 hi, lo;
    #pragma unroll
    for (int j = 0; j < 8; ++j) {
        float s = sv[j] * 64.0f;    // exact pow2 scale: keeps lo out of subnormals
        f16 h = (f16)s;
        hi[j] = h;
        lo[j] = (f16)(s - (float)h);
    }
    int ks   = k >> 5;
    int g    = e >> 4;
    int lane = ((k >> 3) & 3) * 16 + (e & 15);
    size_t dst = ((size_t)(ks * 4 + g) * 64 + lane) * 8;
    *(f16x8*)&wp[dst]         = hi;
    *(f16x8*)&wp[PLANE + dst] = lo;
}

// ---- main: x-stage -> LDS (double-buffered), B-frags from L2, fused top-2 ----
__global__ __launch_bounds__(512, 4)
void topk_gate_kernel(const float* __restrict__ x,
                      const f16* __restrict__ wp,
                      float* __restrict__ out) {
    __shared__ __align__(16) f16 Ah[2][BM * BK];
    __shared__ __align__(16) f16 Al[2][BM * BK];
    __shared__ float red[4][BM][4];

    const int t    = threadIdx.x;
    const int blk  = blockIdx.x;
    const int lane = t & 63;
    const int wid  = t >> 6;       // 0..7
    const int wm   = wid & 1;      // token half (16 tokens)
    const int wn   = wid >> 1;     // expert group (16 experts)
    const int col  = lane & 15;
    const int grp  = lane >> 4;

    // staging: thread t stages A row (t>>4), float4 #(t&15)
    const int srow = t >> 4;
    const int sq4  = t & 15;
    const float* asrc = x + ((size_t)blk * BM + srow) * HID + sq4 * 4;
    const int aoff = swz(srow, sq4 >> 1) + (sq4 & 1) * 4;

    // per-lane B-fragment base (coalesced 16 B/lane); step s, sub s2 at
    // byte-elems offset (2s+s2)*2048
    const f16* bp = wp + ((size_t)(wn * 64 + lane)) * 8;

    f32x4 acc = {0.f, 0.f, 0.f, 0.f};
    const int arow = wm * 16 + col;

    // ---- prologue ----
    float4 a_cur = *(const float4*)(asrc);              // step 0
    {   // convert step 0 -> buf 0
        float4 v = a_cur;
        f16 hx=(f16)v.x, hy=(f16)v.y, hz=(f16)v.z, hw=(f16)v.w;
        *(f16x4*)&Ah[0][aoff] = (f16x4){hx,hy,hz,hw};
        *(f16x4*)&Al[0][aoff] = (f16x4){(f16)(v.x-(float)hx),(f16)(v.y-(float)hy),
                                        (f16)(v.z-(float)hz),(f16)(v.w-(float)hw)};
    }
    float4 a_nxt = *(const float4*)(asrc + BK);         // step 1
    // B prefetch for step 0
    f16x8 bh0c = *(const f16x8*)(bp + 0);
    f16x8 bl0c = *(const f16x8*)(bp + PLANE + 0);
    f16x8 bh1c = *(const f16x8*)(bp + 2048);
    f16x8 bl1c = *(const f16x8*)(bp + PLANE + 2048);
    __syncthreads();

    for (int s = 0; s < NSTEPS; ++s) {
        const int buf = s & 1;
        // prefetch B for step s+1
        const int sn = (s + 1 < NSTEPS) ? (s + 1) : s;
        const size_t bo = (size_t)sn * 4096;
        f16x8 bh0n = *(const f16x8*)(bp + bo);
        f16x8 bl0n = *(const f16x8*)(bp + PLANE + bo);
        f16x8 bh1n = *(const f16x8*)(bp + bo + 2048);
        f16x8 bl1n = *(const f16x8*)(bp + PLANE + bo + 2048);
        // prefetch A for step s+2
        float4 a_n2 = (s + 2 < NSTEPS) ? *(const float4*)(asrc + (size_t)(s + 2) * BK)
                                       : a_nxt;

        // compute step s from LDS[buf] + B regs
        {
            f16x8 ah = *(const f16x8*)&Ah[buf][swz(arow, grp)];
            f16x8 al = *(const f16x8*)&Al[buf][swz(arow, grp)];
            acc = __builtin_amdgcn_mfma_f32_16x16x32_f16(ah, bh0c, acc, 0, 0, 0);
            acc = __builtin_amdgcn_mfma_f32_16x16x32_f16(ah, bl0c, acc, 0, 0, 0);
            acc = __builtin_amdgcn_mfma_f32_16x16x32_f16(al, bh0c, acc, 0, 0, 0);
            ah = *(const f16x8*)&Ah[buf][swz(arow, 4 + grp)];
            al = *(const f16x8*)&Al[buf][swz(arow, 4 + grp)];
            acc = __builtin_amdgcn_mfma_f32_16x16x32_f16(ah, bh1c, acc, 0, 0, 0);
            acc = __builtin_amdgcn_mfma_f32_16x16x32_f16(ah, bl1c, acc, 0, 0, 0);
            acc = __builtin_amdgcn_mfma_f32_16x16x32_f16(al, bh1c, acc, 0, 0, 0);
        }

        // convert step s+1 -> other buffer (no conflict with reads of buf)
        if (s + 1 < NSTEPS) {
            float4 v = a_nxt;
            f16 hx=(f16)v.x, hy=(f16)v.y, hz=(f16)v.z, hw=(f16)v.w;
            *(f16x4*)&Ah[buf ^ 1][aoff] = (f16x4){hx,hy,hz,hw};
            *(f16x4*)&Al[buf ^ 1][aoff] = (f16x4){(f16)(v.x-(float)hx),(f16)(v.y-(float)hy),
                                                  (f16)(v.z-(float)hz),(f16)(v.w-(float)hw)};
        }
        __syncthreads();

        a_nxt = a_n2;
        bh0c = bh0n; bl0c = bl0n; bh1c = bh1n; bl1c = bl1n;
    }

    // ---- epilogue: per-wave top-2 over its 16 experts, then cross-group merge ----
    #pragma unroll
    for (int r = 0; r < 4; ++r) {
        float v0 = acc[r]; int i0 = wn * 16 + col;
        float v1 = -INFINITY; int i1 = 0x7fffffff;
        #pragma unroll
        for (int m = 1; m <= 8; m <<= 1) {
            float ov0 = __shfl_xor(v0, m, 64);
            int   oi0 = __shfl_xor(i0, m, 64);
            float ov1 = __shfl_xor(v1, m, 64);
            int   oi1 = __shfl_xor(i1, m, 64);
            bool ob = (ov0 > v0) || (ov0 == v0 && oi0 < i0);
            if (ob) {
                bool k2 = (v0 > ov1) || (v0 == ov1 && i0 < oi1);
                v1 = k2 ? v0 : ov1; i1 = k2 ? i0 : oi1;
                v0 = ov0; i0 = oi0;
            } else {
                bool k2 = (ov0 > v1) || (ov0 == v1 && oi0 < i1);
                v1 = k2 ? ov0 : v1; i1 = k2 ? oi0 : i1;
            }
        }
        if (col == 0) {
            int tl = wm * 16 + grp * 4 + r;
            red[wn][tl][0] = v0; red[wn][tl][1] = (float)i0;
            red[wn][tl][2] = v1; red[wn][tl][3] = (float)i1;
        }
    }
    __syncthreads();

    if (t < BM) {
        float v0 = red[0][t][0]; int i0 = (int)red[0][t][1];
        float v1 = red[0][t][2]; int i1 = (int)red[0][t][3];
        #pragma unroll
        for (int g = 1; g < 4; ++g) {
            float b0 = red[g][t][0]; int bi0 = (int)red[g][t][1];
            float b1 = red[g][t][2]; int bi1 = (int)red[g][t][3];
            bool bb = (b0 > v0) || (b0 == v0 && bi0 < i0);
            if (bb) {
                bool k2 = (v0 > b1) || (v0 == b1 && i0 < bi1);
                float nv1 = k2 ? v0 : b1; int ni1 = k2 ? i0 : bi1;
                v0 = b0; i0 = bi0; v1 = nv1; i1 = ni1;
            } else {
                bool k2 = (b0 > v1) || (b0 == v1 && bi0 < i1);
                v1 = k2 ? b0 : v1; i1 = k2 ? bi0 : i1;
            }
        }
        // softmax over [v0, v1] (v0 is max; logits were scaled by 64)
        float d  = (v1 - v0) * (1.0f / 64.0f);
        float e  = expf(d);
        float g0 = 1.0f / (1.0f + e);
        float g1 = e / (1.0f + e);

        int tok = blk * BM + t;
        out[(size_t)tok * 2 + 0] = g0;
        out[(size_t)tok * 2 + 1] = g1;
        out[(size_t)NTOK * 2 + (size_t)tok * 2 + 0] = (float)i0;
        out[(size_t)NTOK * 2 + (size_t)tok * 2 + 1] = (float)i1;
    }
}

extern "C" void kernel_launch(void* const* d_in, const int* in_sizes, int n_in,
                              void* d_out, int out_size, void* d_ws, size_t ws_size,
                              hipStream_t stream) {
    const float* x = (const float*)d_in[0];   // [16384, 4096] f32
    const float* w = (const float*)d_in[1];   // [64, 4096] f32
    float* out = (float*)d_out;               // gates [16384,2] then idx-as-f32 [16384,2]
    f16* wp = (f16*)d_ws;                     // 1 MB packed hi/lo planes
    (void)in_sizes; (void)n_in; (void)out_size; (void)ws_size;

    pack_w_kernel<<<dim3(128), dim3(256), 0, stream>>>(w, wp);
    topk_gate_kernel<<<dim3(NTOK / BM), dim3(512), 0, stream>>>(x, wp, out);
}

// Round 3
// 73.133 us; speedup vs baseline: 1.0773x; 1.0773x over previous
//
#include <hip/hip_runtime.h>

#define NTOK 16384
#define HID  4096
#define NEXP 64
#define TOKB 32                 // tokens per block
#define KSPLIT 4                // waves per block; each wave owns HID/KSPLIT k's
#define STEPS (HID / KSPLIT / 64)   // 16 steps of K=64 per wave
#define PLANE  (NEXP * HID)     // 262144 f16 per plane (512 KB)
#define LROW 68                 // padded LDS row (f32) for logits

typedef _Float16 f16;
typedef f16  f16x8 __attribute__((ext_vector_type(8)));
typedef float f32x4 __attribute__((ext_vector_type(4)));

// ---- pack w -> fragment-ordered fp16 hi/lo planes in workspace (R2-proven) ----
// wp[p][ks_glob(128)][g(4)][lane(64)][j(8)]: expert e = g*16+(l&15),
// k = ks_glob*32 + (l>>4)*8 + j.  One B-fragment = 64 lanes x 16 B contiguous.
__global__ __launch_bounds__(256)
void pack_w_kernel(const float* __restrict__ w, f16* __restrict__ wp) {
    int tid = blockIdx.x * 256 + threadIdx.x;   // 32768 threads
    int e = tid >> 9;                           // 0..63
    int k = (tid & 511) << 3;                   // 0..4088, step 8
    const float* src = w + (size_t)e * HID + k;
    float4 v0 = *(const float4*)(src);
    float4 v1 = *(const float4*)(src + 4);
    float sv[8] = {v0.x, v0.y, v0.z, v0.w, v1.x, v1.y, v1.z, v1.w};
    f16x8 hi, lo;
    #pragma unroll
    for (int j = 0; j < 8; ++j) {
        float s = sv[j] * 64.0f;    // exact pow2 scale keeps lo out of subnormals
        f16 h = (f16)s;
        hi[j] = h;
        lo[j] = (f16)(s - (float)h);
    }
    int ks   = k >> 5;
    int g    = e >> 4;
    int lane = ((k >> 3) & 3) * 16 + (e & 15);
    size_t dst = ((size_t)(ks * 4 + g) * 64 + lane) * 8;
    *(f16x8*)&wp[dst]         = hi;
    *(f16x8*)&wp[PLANE + dst] = lo;
}

__device__ __forceinline__ void cvt_hilo(float4 a, float4 b, f16x8& hi, f16x8& lo) {
    float v[8] = {a.x, a.y, a.z, a.w, b.x, b.y, b.z, b.w};
    #pragma unroll
    for (int j = 0; j < 8; ++j) {
        f16 h = (f16)v[j];
        hi[j] = h;
        lo[j] = (f16)(v[j] - (float)h);
    }
}

// ---- main: barrier-free K-loop; x read in fragment order; B frags from L2 ----
__global__ __launch_bounds__(256)
void topk_gate_kernel(const float* __restrict__ x,
                      const f16* __restrict__ wp,
                      float* __restrict__ out) {
    __shared__ float P[KSPLIT][TOKB * LROW];   // partial logits per wave
    __shared__ float F[TOKB * LROW];           // summed logits

    const int t    = threadIdx.x;
    const int blk  = blockIdx.x;
    const int lane = t & 63;
    const int w    = t >> 6;        // 0..3: K-split wave id
    const int col  = lane & 15;
    const int grp  = lane >> 4;

    // A: lane reads x[blk*32 + tm*16 + col][w*1024 + s*64 + ks*32 + grp*8 + j]
    const float* aw = x + ((size_t)blk * TOKB + col) * HID + w * (HID / KSPLIT) + grp * 8;
    // B: fragment (ks_glob, eg, p) at ((ks_glob*4+eg)*64 + lane)*8 (+p*PLANE)
    const f16* bw = wp + (size_t)lane * 8;

    f32x4 acc[2][4];
    #pragma unroll
    for (int tm = 0; tm < 2; ++tm)
        #pragma unroll
        for (int eg = 0; eg < 4; ++eg)
            acc[tm][eg] = (f32x4){0.f, 0.f, 0.f, 0.f};

    // prologue: step-0 A loads
    float4 af[2][2][2];
    #pragma unroll
    for (int tm = 0; tm < 2; ++tm)
        #pragma unroll
        for (int ks = 0; ks < 2; ++ks)
            #pragma unroll
            for (int h = 0; h < 2; ++h)
                af[tm][ks][h] = *(const float4*)(aw + tm * 16 * HID + ks * 32 + h * 4);

    for (int s = 0; s < STEPS; ++s) {
        // B loads for both ks first (max lead time over their MFMA use)
        f16x8 bh[2][4], bl[2][4];
        #pragma unroll
        for (int ks = 0; ks < 2; ++ks) {
            const size_t base = (size_t)((w * 32 + s * 2 + ks) * 4) * 512;
            #pragma unroll
            for (int eg = 0; eg < 4; ++eg) {
                bh[ks][eg] = *(const f16x8*)(bw + base + eg * 512);
                bl[ks][eg] = *(const f16x8*)(bw + base + eg * 512 + PLANE);
            }
        }
        // A prefetch for step s+1 (HBM latency hidden across the step)
        const int sn = (s + 1 < STEPS) ? (s + 1) : s;
        float4 an[2][2][2];
        #pragma unroll
        for (int tm = 0; tm < 2; ++tm)
            #pragma unroll
            for (int ks = 0; ks < 2; ++ks)
                #pragma unroll
                for (int h = 0; h < 2; ++h)
                    an[tm][ks][h] = *(const float4*)(aw + tm * 16 * HID + sn * 64 + ks * 32 + h * 4);

        // convert current A to hi/lo fragments (covers B L2 latency with VALU)
        f16x8 ah[2][2], al[2][2];
        #pragma unroll
        for (int tm = 0; tm < 2; ++tm)
            #pragma unroll
            for (int ks = 0; ks < 2; ++ks)
                cvt_hilo(af[tm][ks][0], af[tm][ks][1], ah[tm][ks], al[tm][ks]);

        // 48 MFMAs: 2 tm x 4 eg x 2 ks x 3 planes
        #pragma unroll
        for (int ks = 0; ks < 2; ++ks)
            #pragma unroll
            for (int tm = 0; tm < 2; ++tm)
                #pragma unroll
                for (int eg = 0; eg < 4; ++eg) {
                    acc[tm][eg] = __builtin_amdgcn_mfma_f32_16x16x32_f16(ah[tm][ks], bh[ks][eg], acc[tm][eg], 0, 0, 0);
                    acc[tm][eg] = __builtin_amdgcn_mfma_f32_16x16x32_f16(ah[tm][ks], bl[ks][eg], acc[tm][eg], 0, 0, 0);
                    acc[tm][eg] = __builtin_amdgcn_mfma_f32_16x16x32_f16(al[tm][ks], bh[ks][eg], acc[tm][eg], 0, 0, 0);
                }

        #pragma unroll
        for (int tm = 0; tm < 2; ++tm)
            #pragma unroll
            for (int ks = 0; ks < 2; ++ks)
                #pragma unroll
                for (int h = 0; h < 2; ++h)
                    af[tm][ks][h] = an[tm][ks][h];
    }

    // ---- epilogue: K-split reduce + fused top-2/softmax ----
    // C layout: lane holds C[row = grp*4 + r][col]; row = local token, col = expert-in-group
    #pragma unroll
    for (int tm = 0; tm < 2; ++tm)
        #pragma unroll
        for (int eg = 0; eg < 4; ++eg)
            #pragma unroll
            for (int r = 0; r < 4; ++r) {
                int tokl = tm * 16 + grp * 4 + r;
                int e    = eg * 16 + col;
                P[w][tokl * LROW + e] = acc[tm][eg][r];
            }
    __syncthreads();

    {   // sum 4 partials: thread t -> token t>>3, experts (t&7)*8 .. +8
        int tok = t >> 3;
        int e0  = (t & 7) * 8;
        #pragma unroll
        for (int j = 0; j < 8; ++j) {
            float ssum = P[0][tok * LROW + e0 + j];
            #pragma unroll
            for (int w2 = 1; w2 < KSPLIT; ++w2)
                ssum += P[w2][tok * LROW + e0 + j];
            F[tok * LROW + e0 + j] = ssum;
        }
    }
    __syncthreads();

    // top-2: wave w handles tokens w*8 .. w*8+7; lane l holds expert l's logit
    for (int tt = 0; tt < 8; ++tt) {
        int tokl = w * 8 + tt;
        float v0 = F[tokl * LROW + lane]; int i0 = lane;
        float v1 = -INFINITY;             int i1 = 0x7fffffff;
        #pragma unroll
        for (int m = 1; m <= 32; m <<= 1) {
            float ov0 = __shfl_xor(v0, m, 64);
            int   oi0 = __shfl_xor(i0, m, 64);
            float ov1 = __shfl_xor(v1, m, 64);
            int   oi1 = __shfl_xor(i1, m, 64);
            bool ob = (ov0 > v0) || (ov0 == v0 && oi0 < i0);
            if (ob) {
                bool k2 = (v0 > ov1) || (v0 == ov1 && i0 < oi1);
                v1 = k2 ? v0 : ov1; i1 = k2 ? i0 : oi1;
                v0 = ov0; i0 = oi0;
            } else {
                bool k2 = (ov0 > v1) || (ov0 == v1 && oi0 < i1);
                v1 = k2 ? ov0 : v1; i1 = k2 ? oi0 : i1;
            }
        }
        if (lane == 0) {
            // softmax over [v0, v1]; logits were scaled by 64 via w
            float d  = (v1 - v0) * (1.0f / 64.0f);
            float e  = expf(d);
            float g0 = 1.0f / (1.0f + e);
            float g1 = e / (1.0f + e);
            int tok = blk * TOKB + tokl;
            out[(size_t)tok * 2 + 0] = g0;
            out[(size_t)tok * 2 + 1] = g1;
            out[(size_t)NTOK * 2 + (size_t)tok * 2 + 0] = (float)i0;
            out[(size_t)NTOK * 2 + (size_t)tok * 2 + 1] = (float)i1;
        }
    }
}

extern "C" void kernel_launch(void* const* d_in, const int* in_sizes, int n_in,
                              void* d_out, int out_size, void* d_ws, size_t ws_size,
                              hipStream_t stream) {
    const float* x = (const float*)d_in[0];   // [16384, 4096] f32
    const float* w = (const float*)d_in[1];   // [64, 4096] f32
    float* out = (float*)d_out;               // gates [16384,2] then idx-as-f32 [16384,2]
    f16* wp = (f16*)d_ws;                     // 1 MB packed hi/lo planes
    (void)in_sizes; (void)n_in; (void)out_size; (void)ws_size;

    pack_w_kernel<<<dim3(128), dim3(256), 0, stream>>>(w, wp);
    topk_gate_kernel<<<dim3(NTOK / TOKB), dim3(256), 0, stream>>>(x, wp, out);
}